// Round 3
// baseline (166.045 us; speedup 1.0000x reference)
//
#include <hip/hip_runtime.h>

// CrumbReconstructor R6: codebook in wave-distributed VGPRs, rows broadcast
// via v_readlane. NO memory pipe in the hot loop.
//
// R5 post-mortem: every prior variant bottlenecked on a per-CU shared memory
// pipe: R3 = LDS pipe (3.2M ds_read_b128 ~= 62us, matches 71us runtime),
// R4/R5 = scalar-cache with unordered-SMEM lgkmcnt(0) drains. R5 also added
// 1.3x block-quantization imbalance (784 coarse blocks, 3.06/CU).
//
// Fix: codebook = 2048 floats = 32 VGPR/lane distributed across the wave
// (lane l owns rows l, l+64, l+128, l+192 + norms). Per row, broadcast the
// owner lane's 8 elems + norm with 9 v_readlane ops: pure VALU, no waits,
// no LDS/SMEM traffic, broadcast result is an SGPR (free fma operand).
// Hot loop/row: 9 readlane + 4 keys x 13 = 61 instr -> ~39us issue floor.
// BLOCK=64 one-wave blocks: 3136 blocks = 12.25/CU, 6% imbalance (vs 30%).
// LDS deleted; final gather re-reads the L1-hot 8KB codebook from global.
//
// Bit-identity (absmax must stay 0.0): row visit order is m=0..255
// (c-major, lane-minor = identical sequence), dot is the same sequential
// fmaf chain, d = fmaf(dot,-2,knorm)+rn, strict < (first index wins ties).

#define LBLK 8      // memblock length
#define NROW 256    // codebook rows
#define TPK 4       // key-blocks per thread
#define BLOCK 64    // threads per workgroup = 1 wave
#define NCH 4       // row chunks: row m owned by lane (m&63), chunk (m>>6)

__device__ __forceinline__ float bcast(float v, int l) {
    return __int_as_float(__builtin_amdgcn_readlane(__float_as_int(v), l));
}

__global__ __launch_bounds__(BLOCK, 4) void crumb_kernel(
    const float* __restrict__ x,
    const float* __restrict__ mem,
    float* __restrict__ out,
    int nblocks)
{
    const int lane = threadIdx.x;

    // --- codebook into wave-distributed registers (coalesced 2KB per chunk) ---
    float rd[NCH][LBLK];
    float rnorm[NCH];
    #pragma unroll
    for (int c = 0; c < NCH; ++c) {
        const float4* g = (const float4*)(mem + (c * 64 + lane) * LBLK);
        float4 a = g[0], b = g[1];
        rd[c][0] = a.x; rd[c][1] = a.y; rd[c][2] = a.z; rd[c][3] = a.w;
        rd[c][4] = b.x; rd[c][5] = b.y; rd[c][6] = b.z; rd[c][7] = b.w;
        float q0 = a.x * a.x, q1 = a.y * a.y, q2 = a.z * a.z, q3 = a.w * a.w;
        float q4 = b.x * b.x, q5 = b.y * b.y, q6 = b.z * b.z, q7 = b.w * b.w;
        rnorm[c] = ((q0 + q1) + (q2 + q3)) + ((q4 + q5) + (q6 + q7));
    }

    // --- load keys (4 per thread, coalesced 2KB per t) ---
    const long base = (long)blockIdx.x * (BLOCK * TPK) + lane;

    float k[TPK][LBLK];
    float knorm[TPK];
    long  kb[TPK];
    bool  valid[TPK];

    #pragma unroll
    for (int t = 0; t < TPK; ++t) {
        long b0 = base + (long)t * BLOCK;
        valid[t] = (b0 < (long)nblocks);
        kb[t] = valid[t] ? b0 : 0;
        const float4* g = (const float4*)(x + kb[t] * LBLK);
        float4 a = g[0], b = g[1];
        k[t][0] = a.x; k[t][1] = a.y; k[t][2] = a.z; k[t][3] = a.w;
        k[t][4] = b.x; k[t][5] = b.y; k[t][6] = b.z; k[t][7] = b.w;
        float q0 = a.x * a.x, q1 = a.y * a.y, q2 = a.z * a.z, q3 = a.w * a.w;
        float q4 = b.x * b.x, q5 = b.y * b.y, q6 = b.z * b.z, q7 = b.w * b.w;
        knorm[t] = ((q0 + q1) + (q2 + q3)) + ((q4 + q5) + (q6 + q7));
    }

    float best[TPK];
    int   bidx[TPK];
    #pragma unroll
    for (int t = 0; t < TPK; ++t) { best[t] = 3.4e38f; bidx[t] = 0; }

    // --- scan all 256 rows; broadcast each from its owner lane, pure VALU ---
    #pragma unroll
    for (int c = 0; c < NCH; ++c) {
        #pragma unroll 4
        for (int l = 0; l < 64; ++l) {      // row m = c*64 + l, in order
            float r0 = bcast(rd[c][0], l);
            float r1 = bcast(rd[c][1], l);
            float r2 = bcast(rd[c][2], l);
            float r3 = bcast(rd[c][3], l);
            float r4 = bcast(rd[c][4], l);
            float r5 = bcast(rd[c][5], l);
            float r6 = bcast(rd[c][6], l);
            float r7 = bcast(rd[c][7], l);
            float rn = bcast(rnorm[c], l);
            const int m = c * 64 + l;

            #pragma unroll
            for (int t = 0; t < TPK; ++t) {
                float dot = k[t][0] * r0;
                dot = fmaf(k[t][1], r1, dot);
                dot = fmaf(k[t][2], r2, dot);
                dot = fmaf(k[t][3], r3, dot);
                dot = fmaf(k[t][4], r4, dot);
                dot = fmaf(k[t][5], r5, dot);
                dot = fmaf(k[t][6], r6, dot);
                dot = fmaf(k[t][7], r7, dot);
                float d = fmaf(dot, -2.0f, knorm[t]) + rn;
                // strict < : first (lowest) index wins exact ties (= argmin)
                if (d < best[t]) { best[t] = d; bidx[t] = m; }
            }
        }
    }

    // --- gather winning rows from global codebook (8KB, L1-hot), store ---
    #pragma unroll
    for (int t = 0; t < TPK; ++t) {
        if (valid[t]) {
            const float4* g = (const float4*)(mem + (long)bidx[t] * LBLK);
            float4 a = g[0], b = g[1];
            float4* o = (float4*)(out + kb[t] * LBLK);
            o[0] = a;
            o[1] = b;
        }
    }
}

extern "C" void kernel_launch(void* const* d_in, const int* in_sizes, int n_in,
                              void* d_out, int out_size, void* d_ws, size_t ws_size,
                              hipStream_t stream) {
    const float* x   = (const float*)d_in[0];
    const float* mem = (const float*)d_in[1];
    float* out = (float*)d_out;

    int n = in_sizes[0];            // total x elements
    int nblocks = n / LBLK;         // key-blocks
    int grid = (nblocks + BLOCK * TPK - 1) / (BLOCK * TPK);

    hipLaunchKernelGGL(crumb_kernel, dim3(grid), dim3(BLOCK), 0, stream,
                       x, mem, out, nblocks);
}

// Round 4
// 139.770 us; speedup vs baseline: 1.1880x; 1.1880x over previous
//
#include <hip/hip_runtime.h>

// CrumbReconstructor R7: R3's LDS-broadcast row loop + exact load balance.
//
// Model that finally fits all rounds: per-CU LDS pipe cost per wave per row =
// 2x ds_read_b128 (~12cy) + ds_read_b32 (~6cy) ~= 30 cy. R3 (24.5 waves/CU):
// 24.5*256*30 = 188Kcy = 78us — matches its 71-74us. LDS traffic scales with
// waves/CU; VALU floor is 34us (13 ops/key/row). R5's regression was block
// quantization (3.06 blocks/CU -> 1.3x stretch); R6's readlane chain stalled
// on VALU->SGPR hazards.
//
// Fix: more keys per wave + exact balance, same proven row loop:
//  - 2048 one-wave blocks = exactly 8/CU, 2 waves/SIMD. No CU quantization.
//  - 12544 groups (64 keys each) = 2048*6 + 256. blockIdx bit-swizzle
//    bp = ((b&7)<<8)|(b>>3) puts exactly ONE 7-group wave per CU -> every CU
//    carries a uniform 49 groups. Worst SIMD = 13 groups ~= 36us issue.
//  - LDS pipe now 8 waves/CU * 7680cy = 25us < VALU floor -> not the limit.
//  - Per-row compute (>=6*13*2 = 156cy) covers ~120cy ds latency with the
//    R3-proven 1-row-ahead register prefetch.
//  - scan<G> template (G=6,7) keeps all arrays statically indexed.
//
// Hot-loop math bit-identical to R3 (absmax 0.0): sequential fmaf dot,
// fmaf(dot,-2,knorm)+rn, strict < (first/lowest index wins exact ties).

#define LBLK 8          // memblock length
#define NROW 256        // codebook rows
#define BLOCK 64        // 1 wave per block
#define TARGET_BLOCKS 2048  // 8 blocks/CU on 256 CUs

template<int G>
__device__ __forceinline__ void scan_groups(
    const float* __restrict__ x,
    float* __restrict__ out,
    const float* __restrict__ s_mem,
    const float* __restrict__ s_norm,
    const int* gi,          // G group indices (each = 64 keys)
    int nblocks, int lane)
{
    float k[G][LBLK];
    float knorm[G];
    int   kb[G];
    bool  valid[G];

    #pragma unroll
    for (int t = 0; t < G; ++t) {
        int b0 = gi[t] * 64 + lane;
        valid[t] = (b0 < nblocks);
        kb[t] = valid[t] ? b0 : 0;
        const float4* g = (const float4*)(x + (long)kb[t] * LBLK);
        float4 a = g[0], b = g[1];
        k[t][0] = a.x; k[t][1] = a.y; k[t][2] = a.z; k[t][3] = a.w;
        k[t][4] = b.x; k[t][5] = b.y; k[t][6] = b.z; k[t][7] = b.w;
        float q0 = a.x * a.x, q1 = a.y * a.y, q2 = a.z * a.z, q3 = a.w * a.w;
        float q4 = b.x * b.x, q5 = b.y * b.y, q6 = b.z * b.z, q7 = b.w * b.w;
        knorm[t] = ((q0 + q1) + (q2 + q3)) + ((q4 + q5) + (q6 + q7));
    }

    float best[G];
    int   bidx[G];
    #pragma unroll
    for (int t = 0; t < G; ++t) { best[t] = 3.4e38f; bidx[t] = 0; }

    // --- score all 256 rows; LDS broadcast + 1-row-ahead register prefetch ---
    float4 ra = ((const float4*)s_mem)[0];
    float4 rb = ((const float4*)s_mem)[1];
    float  rn = s_norm[0];

    #pragma unroll 4
    for (int m = 0; m < NROW; ++m) {
        const int mn = (m + 1) & (NROW - 1);
        float4 na = ((const float4*)s_mem)[mn * 2 + 0];
        float4 nb = ((const float4*)s_mem)[mn * 2 + 1];
        float  nn = s_norm[mn];

        #pragma unroll
        for (int t = 0; t < G; ++t) {
            float dot = k[t][0] * ra.x;
            dot = fmaf(k[t][1], ra.y, dot);
            dot = fmaf(k[t][2], ra.z, dot);
            dot = fmaf(k[t][3], ra.w, dot);
            dot = fmaf(k[t][4], rb.x, dot);
            dot = fmaf(k[t][5], rb.y, dot);
            dot = fmaf(k[t][6], rb.z, dot);
            dot = fmaf(k[t][7], rb.w, dot);
            float d = fmaf(dot, -2.0f, knorm[t]) + rn;
            // strict < : first (lowest) index wins exact ties (= argmin)
            if (d < best[t]) { best[t] = d; bidx[t] = m; }
        }

        ra = na; rb = nb; rn = nn;
    }

    // --- gather winning rows from LDS, store ---
    #pragma unroll
    for (int t = 0; t < G; ++t) {
        if (valid[t]) {
            float4* o = (float4*)(out + (long)kb[t] * LBLK);
            o[0] = ((const float4*)s_mem)[bidx[t] * 2 + 0];
            o[1] = ((const float4*)s_mem)[bidx[t] * 2 + 1];
        }
    }
}

__global__ __launch_bounds__(BLOCK, 2) void crumb_kernel(
    const float* __restrict__ x,
    const float* __restrict__ mem,
    float* __restrict__ out,
    int nblocks, int gbase, int gextra)
{
    __shared__ float s_mem[NROW * LBLK];   // 8 KB, rows contiguous
    __shared__ float s_norm[NROW];         // 1 KB

    const int lane = threadIdx.x;

    // --- stage codebook: 4 rows per thread, coalesced ---
    {
        const float4* g = (const float4*)mem;
        #pragma unroll
        for (int c = 0; c < 4; ++c) {
            const int rr = c * 64 + lane;
            float4 a = g[rr * 2 + 0];
            float4 b = g[rr * 2 + 1];
            ((float4*)s_mem)[rr * 2 + 0] = a;
            ((float4*)s_mem)[rr * 2 + 1] = b;
            float q0 = a.x * a.x, q1 = a.y * a.y, q2 = a.z * a.z, q3 = a.w * a.w;
            float q4 = b.x * b.x, q5 = b.y * b.y, q6 = b.z * b.z, q7 = b.w * b.w;
            s_norm[rr] = ((q0 + q1) + (q2 + q3)) + ((q4 + q5) + (q6 + q7));
        }
    }
    __syncthreads();

    // --- balanced group assignment ---
    // bp bijection on [0,2048): spreads the 256 (gbase+1)-group waves so each
    // CU (8 consecutive blocks) gets exactly one. Identity for odd grids.
    const int b = blockIdx.x;
    const int bp = (gridDim.x == TARGET_BLOCKS) ? (((b & 7) << 8) | (b >> 3)) : b;
    const int g = gbase + (bp < gextra ? 1 : 0);
    const int stride = gridDim.x;

    if (g == 7) {
        int gi[7];
        #pragma unroll
        for (int j = 0; j < 7; ++j) gi[j] = j * stride + bp;
        scan_groups<7>(x, out, s_mem, s_norm, gi, nblocks, lane);
    } else if (g == 6) {
        int gi[6];
        #pragma unroll
        for (int j = 0; j < 6; ++j) gi[j] = j * stride + bp;
        scan_groups<6>(x, out, s_mem, s_norm, gi, nblocks, lane);
    } else {
        // generic fallback for non-standard shapes: one group at a time
        for (int j = 0; j < g; ++j) {
            int gi1[1] = { j * stride + bp };
            scan_groups<1>(x, out, s_mem, s_norm, gi1, nblocks, lane);
        }
    }
}

extern "C" void kernel_launch(void* const* d_in, const int* in_sizes, int n_in,
                              void* d_out, int out_size, void* d_ws, size_t ws_size,
                              hipStream_t stream) {
    const float* x   = (const float*)d_in[0];
    const float* mem = (const float*)d_in[1];
    float* out = (float*)d_out;

    int n = in_sizes[0];                 // total x elements
    int nblocks = n / LBLK;              // key-blocks (802816 for std shape)
    int ngroups = (nblocks + 63) / 64;   // 64-key groups (12544)

    int grid = (ngroups < TARGET_BLOCKS) ? (ngroups > 0 ? ngroups : 1)
                                         : TARGET_BLOCKS;
    int gbase  = ngroups / grid;         // 6 for std shape
    int gextra = ngroups % grid;         // 256 for std shape

    hipLaunchKernelGGL(crumb_kernel, dim3(grid), dim3(BLOCK), 0, stream,
                       x, mem, out, nblocks, gbase, gextra);
}